// Round 4
// baseline (720.821 us; speedup 1.0000x reference)
//
#include <hip/hip_runtime.h>

#define BB 1024
#define FF 64
#define SS 512
#define HH 128
#define ZP 328          // z row pitch in bf16 elems (320 data + 8 pad; mult of 8 -> 16B-aligned b128)
#define ZROWS 16

typedef __attribute__((ext_vector_type(8))) short bf16x8;
typedef __attribute__((ext_vector_type(4))) float f32x4;

__device__ __forceinline__ unsigned short f2bf(float f) {
    unsigned int u = __float_as_uint(f);
    u += 0x7fff + ((u >> 16) & 1);          // RNE
    return (unsigned short)(u >> 16);
}

// ---------------------------------------------------------------------------
// Fold kernel: W_fold[n][k] = sum_f W_ih[n][f]*W_den[f][k],
// b_fold[n] = sum_f W_ih[n][f]*b_den[f].  ws[0..65535]=W_fold, ws[65536..]=b_fold.
// ---------------------------------------------------------------------------
__global__ void fold_kernel(const float* __restrict__ W_ih,
                            const float* __restrict__ W_den,
                            const float* __restrict__ b_den,
                            float* __restrict__ ws)
{
    const int n = blockIdx.x;      // 512
    const int k = threadIdx.x;     // 128
    float s = 0.f;
    #pragma unroll 8
    for (int f = 0; f < FF; ++f) s = fmaf(W_ih[n*FF + f], W_den[f*HH + k], s);
    ws[n*HH + k] = s;
    if (k == 0) {
        float bsum = 0.f;
        #pragma unroll 8
        for (int f = 0; f < FF; ++f) bsum = fmaf(W_ih[n*FF + f], b_den[f], bsum);
        ws[4*HH*HH + n] = bsum;    // 65536 + n
    }
}

// ---------------------------------------------------------------------------
// Main recurrence. 256 blocks x 512 threads (8 waves, ONE block per CU).
// Block owns 4 batch rows at M-rows {0,4,8,12} (real rows in acc reg 0).
// One barrier per step. z = [x | h_teacher | h_auto]; B = [W_ih|W_hh|W_auto].
// Autoregressive feedback folded into W_auto = W_hh + W_ih@W_den -> pred never
// feeds back; pred_{t-1} computed at step t from the same h fragments and
// stored EARLY so the pre-barrier vmcnt drain hides under the gate MFMAs.
// NOTE: single-arg launch_bounds -> VGPR cap 256 (two-arg (512,2) caps at 128
// and spilled the weight fragments in rounds 1-3).
// ---------------------------------------------------------------------------
__global__ __launch_bounds__(512)
void lstm_mfma_kernel(const float* __restrict__ x,
                      const int* __restrict__ available_len,
                      const int* __restrict__ predict_len,
                      const float* __restrict__ W_ih,
                      const float* __restrict__ W_hh,
                      const float* __restrict__ b_ih,
                      const float* __restrict__ b_hh,
                      const float* __restrict__ W_den,
                      const float* __restrict__ b_den,
                      const float* __restrict__ init_ch,
                      const float* __restrict__ ws,      // fold results (fp32)
                      float* __restrict__ out)
{
    const int b0  = blockIdx.x * 4;
    const int tid = threadIdx.x;
    const int w   = tid >> 6;          // wave 0..7
    const int l   = tid & 63;
    const int l16 = l & 15;
    const int lq  = l >> 4;            // 0..3
    const bool w4 = (w < 4);

    __shared__ __align__(16) unsigned short zbuf[2][ZROWS * ZP];

    for (int i = tid; i < 2 * ZROWS * ZP / 2; i += 512)
        ((unsigned int*)zbuf)[i] = 0u;

    const int a0v = available_len[b0], a1v = available_len[b0+1],
              a2v = available_len[b0+2], a3v = available_len[b0+3];
    const int p0 = predict_len[b0], p1 = predict_len[b0+1],
              p2 = predict_len[b0+2], p3 = predict_len[b0+3];
    const int maxP  = max(max(p0, p1), max(p2, p3));
    const int minAV = min(min(a0v, a1v), min(a2v, a3v));
    const int maxAV = max(max(a0v, a1v), max(a2v, a3v));
    const int P_my  = predict_len[b0 + lq];
    const int AV_my = available_len[b0 + lq];

    // ---- weight fragments: wg[gate][ktile 0..9], bf16, register-resident ----
    bf16x8 wg[4][10];
    float bias_t[4], bias_a[4];
    const float* wfold = ws;
    const float* bfold = ws + 4*HH*HH;
    #pragma unroll
    for (int g = 0; g < 4; ++g) {
        const int n = 128*g + 16*w + l16;
        const float* rih = W_ih  + n * FF;
        const float* rhh = W_hh  + n * HH;
        const float* rfo = wfold + n * HH;
        #pragma unroll
        for (int kt = 0; kt < 2; ++kt) {          // W_ih ktiles
            const int k = 32*kt + 8*lq;
            bf16x8 r;
            #pragma unroll
            for (int i = 0; i < 8; i++) r[i] = (short)f2bf(rih[k + i]);
            wg[g][kt] = r;
        }
        #pragma unroll
        for (int kt = 0; kt < 4; ++kt) {          // W_hh ktiles
            const int k = 32*kt + 8*lq;
            bf16x8 r;
            #pragma unroll
            for (int i = 0; i < 8; i++) r[i] = (short)f2bf(rhh[k + i]);
            wg[g][2 + kt] = r;
        }
        #pragma unroll
        for (int kt = 0; kt < 4; ++kt) {          // W_auto = W_hh + W_fold ktiles
            const int k = 32*kt + 8*lq;
            bf16x8 r;
            #pragma unroll
            for (int i = 0; i < 8; i++) r[i] = (short)f2bf(rhh[k + i] + rfo[k + i]);
            wg[g][6 + kt] = r;
        }
        bias_t[g] = b_ih[n] + b_hh[n];
        bias_a[g] = bias_t[g] + bfold[n];
    }

    // pred weights (waves 0-3): f = 16w + l16
    bf16x8 wd[4];
    float bden = 0.f;
    size_t xbase = 0;
    int AV_x = 0;
    if (w4) {
        const int f = 16*w + l16;
        const float* rd = W_den + f * HH;
        #pragma unroll
        for (int kt = 0; kt < 4; ++kt) {
            const int k = 32*kt + 8*lq;
            bf16x8 r;
            #pragma unroll
            for (int i = 0; i < 8; i++) r[i] = (short)f2bf(rd[k + i]);
            wd[kt] = r;
        }
        bden = b_den[f];
        xbase = ((size_t)(b0 + w) * FF + l) * SS;
        AV_x  = available_len[b0 + w];
    }

    const int unit = 16*w + l16;
    float c = init_ch[unit];
    const float h0v = init_ch[HH + unit];

    __syncthreads();                    // zeroing complete

    // init buf0: h0 -> teacher slot (t=0 < AV always), x0 -> x slot
    zbuf[0][(4*lq)*ZP + 64 + unit] = f2bf(h0v);
    if (w4) zbuf[0][(4*w)*ZP + l] = f2bf(x[xbase]);

    int cur = 0;
    for (int t = 0; t <= maxP; ++t) {
        __syncthreads();                               // B1 (only barrier)
        const unsigned short* zc = zbuf[cur];
        const bool anyT = (t < maxAV);
        const bool anyA = (t >= minAV);
        const bool last = (t == maxP);
        const bool dop  = w4 && (t > 0);
        const int abase = l16*ZP + 8*lq;

        // x prefetch: issue first, consume last
        float xv = 0.f;
        const bool xl = w4 && !last && (t + 1 < AV_x);
        if (xl) xv = x[xbase + t + 1];

        // ---- fragment loads (each LDS word read exactly once) ----
        bf16x8 a0, a1, hT0, hT1, hT2, hT3, hA0, hA1, hA2, hA3;
        if (anyT) {
            hT0 = *(const bf16x8*)(zc + abase +  64);
            hT1 = *(const bf16x8*)(zc + abase +  96);
            hT2 = *(const bf16x8*)(zc + abase + 128);
            hT3 = *(const bf16x8*)(zc + abase + 160);
            if (!last) {
                a0 = *(const bf16x8*)(zc + abase +  0);
                a1 = *(const bf16x8*)(zc + abase + 32);
            }
        }
        if (anyA) {
            hA0 = *(const bf16x8*)(zc + abase + 192);
            hA1 = *(const bf16x8*)(zc + abase + 224);
            hA2 = *(const bf16x8*)(zc + abase + 256);
            hA3 = *(const bf16x8*)(zc + abase + 288);
        }

        // ---- deferred pred for out[t-1], stored EARLY (drains under gates) --
        if (dop) {
            f32x4 pa = {0.f,0.f,0.f,0.f};
            if (anyT) {
                pa = __builtin_amdgcn_mfma_f32_16x16x32_bf16(hT0, wd[0], pa, 0,0,0);
                pa = __builtin_amdgcn_mfma_f32_16x16x32_bf16(hT1, wd[1], pa, 0,0,0);
                pa = __builtin_amdgcn_mfma_f32_16x16x32_bf16(hT2, wd[2], pa, 0,0,0);
                pa = __builtin_amdgcn_mfma_f32_16x16x32_bf16(hT3, wd[3], pa, 0,0,0);
            }
            if (anyA) {
                pa = __builtin_amdgcn_mfma_f32_16x16x32_bf16(hA0, wd[0], pa, 0,0,0);
                pa = __builtin_amdgcn_mfma_f32_16x16x32_bf16(hA1, wd[1], pa, 0,0,0);
                pa = __builtin_amdgcn_mfma_f32_16x16x32_bf16(hA2, wd[2], pa, 0,0,0);
                pa = __builtin_amdgcn_mfma_f32_16x16x32_bf16(hA3, wd[3], pa, 0,0,0);
            }
            if (t - 1 < P_my)
                out[(size_t)(t-1) * BB * FF + (size_t)(b0 + lq) * FF + 16*w + l16] = pa[0] + bden;
        }

        if (!last) {
            f32x4 ac0 = {0.f,0.f,0.f,0.f}, ac1 = {0.f,0.f,0.f,0.f},
                  ac2 = {0.f,0.f,0.f,0.f}, ac3 = {0.f,0.f,0.f,0.f};
            if (anyT) {
                ac0 = __builtin_amdgcn_mfma_f32_16x16x32_bf16(a0, wg[0][0], ac0, 0,0,0);
                ac1 = __builtin_amdgcn_mfma_f32_16x16x32_bf16(a0, wg[1][0], ac1, 0,0,0);
                ac2 = __builtin_amdgcn_mfma_f32_16x16x32_bf16(a0, wg[2][0], ac2, 0,0,0);
                ac3 = __builtin_amdgcn_mfma_f32_16x16x32_bf16(a0, wg[3][0], ac3, 0,0,0);
                ac0 = __builtin_amdgcn_mfma_f32_16x16x32_bf16(a1, wg[0][1], ac0, 0,0,0);
                ac1 = __builtin_amdgcn_mfma_f32_16x16x32_bf16(a1, wg[1][1], ac1, 0,0,0);
                ac2 = __builtin_amdgcn_mfma_f32_16x16x32_bf16(a1, wg[2][1], ac2, 0,0,0);
                ac3 = __builtin_amdgcn_mfma_f32_16x16x32_bf16(a1, wg[3][1], ac3, 0,0,0);
                ac0 = __builtin_amdgcn_mfma_f32_16x16x32_bf16(hT0, wg[0][2], ac0, 0,0,0);
                ac1 = __builtin_amdgcn_mfma_f32_16x16x32_bf16(hT0, wg[1][2], ac1, 0,0,0);
                ac2 = __builtin_amdgcn_mfma_f32_16x16x32_bf16(hT0, wg[2][2], ac2, 0,0,0);
                ac3 = __builtin_amdgcn_mfma_f32_16x16x32_bf16(hT0, wg[3][2], ac3, 0,0,0);
                ac0 = __builtin_amdgcn_mfma_f32_16x16x32_bf16(hT1, wg[0][3], ac0, 0,0,0);
                ac1 = __builtin_amdgcn_mfma_f32_16x16x32_bf16(hT1, wg[1][3], ac1, 0,0,0);
                ac2 = __builtin_amdgcn_mfma_f32_16x16x32_bf16(hT1, wg[2][3], ac2, 0,0,0);
                ac3 = __builtin_amdgcn_mfma_f32_16x16x32_bf16(hT1, wg[3][3], ac3, 0,0,0);
                ac0 = __builtin_amdgcn_mfma_f32_16x16x32_bf16(hT2, wg[0][4], ac0, 0,0,0);
                ac1 = __builtin_amdgcn_mfma_f32_16x16x32_bf16(hT2, wg[1][4], ac1, 0,0,0);
                ac2 = __builtin_amdgcn_mfma_f32_16x16x32_bf16(hT2, wg[2][4], ac2, 0,0,0);
                ac3 = __builtin_amdgcn_mfma_f32_16x16x32_bf16(hT2, wg[3][4], ac3, 0,0,0);
                ac0 = __builtin_amdgcn_mfma_f32_16x16x32_bf16(hT3, wg[0][5], ac0, 0,0,0);
                ac1 = __builtin_amdgcn_mfma_f32_16x16x32_bf16(hT3, wg[1][5], ac1, 0,0,0);
                ac2 = __builtin_amdgcn_mfma_f32_16x16x32_bf16(hT3, wg[2][5], ac2, 0,0,0);
                ac3 = __builtin_amdgcn_mfma_f32_16x16x32_bf16(hT3, wg[3][5], ac3, 0,0,0);
            }
            if (anyA) {
                ac0 = __builtin_amdgcn_mfma_f32_16x16x32_bf16(hA0, wg[0][6], ac0, 0,0,0);
                ac1 = __builtin_amdgcn_mfma_f32_16x16x32_bf16(hA0, wg[1][6], ac1, 0,0,0);
                ac2 = __builtin_amdgcn_mfma_f32_16x16x32_bf16(hA0, wg[2][6], ac2, 0,0,0);
                ac3 = __builtin_amdgcn_mfma_f32_16x16x32_bf16(hA0, wg[3][6], ac3, 0,0,0);
                ac0 = __builtin_amdgcn_mfma_f32_16x16x32_bf16(hA1, wg[0][7], ac0, 0,0,0);
                ac1 = __builtin_amdgcn_mfma_f32_16x16x32_bf16(hA1, wg[1][7], ac1, 0,0,0);
                ac2 = __builtin_amdgcn_mfma_f32_16x16x32_bf16(hA1, wg[2][7], ac2, 0,0,0);
                ac3 = __builtin_amdgcn_mfma_f32_16x16x32_bf16(hA1, wg[3][7], ac3, 0,0,0);
                ac0 = __builtin_amdgcn_mfma_f32_16x16x32_bf16(hA2, wg[0][8], ac0, 0,0,0);
                ac1 = __builtin_amdgcn_mfma_f32_16x16x32_bf16(hA2, wg[1][8], ac1, 0,0,0);
                ac2 = __builtin_amdgcn_mfma_f32_16x16x32_bf16(hA2, wg[2][8], ac2, 0,0,0);
                ac3 = __builtin_amdgcn_mfma_f32_16x16x32_bf16(hA2, wg[3][8], ac3, 0,0,0);
                ac0 = __builtin_amdgcn_mfma_f32_16x16x32_bf16(hA3, wg[0][9], ac0, 0,0,0);
                ac1 = __builtin_amdgcn_mfma_f32_16x16x32_bf16(hA3, wg[1][9], ac1, 0,0,0);
                ac2 = __builtin_amdgcn_mfma_f32_16x16x32_bf16(hA3, wg[2][9], ac2, 0,0,0);
                ac3 = __builtin_amdgcn_mfma_f32_16x16x32_bf16(hA3, wg[3][9], ac3, 0,0,0);
            }

            const bool auto_my = (t >= AV_my);
            const float g0 = ac0[0] + (auto_my ? bias_a[0] : bias_t[0]);
            const float g1 = ac1[0] + (auto_my ? bias_a[1] : bias_t[1]);
            const float g2 = ac2[0] + (auto_my ? bias_a[2] : bias_t[2]);
            const float g3 = ac3[0] + (auto_my ? bias_a[3] : bias_t[3]);

            const float si = 1.f / (1.f + __expf(-g0));
            const float sf = 1.f / (1.f + __expf(-g1));
            const float tg = 1.f - 2.f / (__expf(2.f * g2) + 1.f);
            const float so = 1.f / (1.f + __expf(-g3));
            const float cn = sf * c + si * tg;
            const float tc = 1.f - 2.f / (__expf(2.f * cn) + 1.f);
            const float hn = so * tc;

            const bool sel = (t < P_my);
            if (sel) c = cn;

            const int nxt = cur ^ 1;
            const unsigned short hbf = f2bf(hn);
            const bool teach_next = (t + 1 < AV_my);
            if (sel) {
                zbuf[nxt][(4*lq)*ZP +  64 + unit] = teach_next ? hbf : (unsigned short)0;
                zbuf[nxt][(4*lq)*ZP + 192 + unit] = teach_next ? (unsigned short)0 : hbf;
            }
            if (w4) zbuf[nxt][(4*w)*ZP + l] = xl ? f2bf(xv) : (unsigned short)0;
            cur = nxt;
        }
    }
}

// ---------------------------------------------------------------------------
// Tail: for t >= predict_len[b], out[t][b][f] = x[b][f][t].
// ---------------------------------------------------------------------------
__global__ void tail_copy(const float* __restrict__ x,
                          const int* __restrict__ predict_len,
                          float* __restrict__ out)
{
    __shared__ float tile[64][65];
    const int b  = blockIdx.x;
    const int t0 = blockIdx.y * 64;
    const int P  = predict_len[b];
    if (t0 + 64 <= P) return;

    const int tid = threadIdx.x;         // 256
    const int tt  = tid & 63;
    const int fb  = tid >> 6;
    #pragma unroll
    for (int i = 0; i < 16; i++) {
        int f = fb * 16 + i;
        tile[f][tt] = x[(size_t)b * FF * SS + (size_t)f * SS + t0 + tt];
    }
    __syncthreads();
    const int f2 = tid & 63;
    const int tb = tid >> 6;
    #pragma unroll
    for (int i = 0; i < 16; i++) {
        int tloc = tb * 16 + i;
        int t    = t0 + tloc;
        if (t >= P) out[(size_t)t * BB * FF + (size_t)b * FF + f2] = tile[f2][tloc];
    }
}

extern "C" void kernel_launch(void* const* d_in, const int* in_sizes, int n_in,
                              void* d_out, int out_size, void* d_ws, size_t ws_size,
                              hipStream_t stream) {
    const float* x       = (const float*)d_in[0];
    const int*   avail   = (const int*)  d_in[1];
    const int*   plen    = (const int*)  d_in[2];
    const float* W_ih    = (const float*)d_in[3];
    const float* W_hh    = (const float*)d_in[4];
    const float* b_ih    = (const float*)d_in[5];
    const float* b_hh    = (const float*)d_in[6];
    const float* W_den   = (const float*)d_in[7];
    const float* b_den   = (const float*)d_in[8];
    const float* init_ch = (const float*)d_in[9];
    float*       out     = (float*)d_out;
    float*       ws      = (float*)d_ws;       // needs 264 KB

    fold_kernel<<<dim3(4*HH), dim3(HH), 0, stream>>>(W_ih, W_den, b_den, ws);
    tail_copy<<<dim3(BB, SS/64), dim3(256), 0, stream>>>(x, plen, out);
    lstm_mfma_kernel<<<dim3(BB/4), dim3(512), 0, stream>>>(
        x, avail, plen, W_ih, W_hh, b_ih, b_hh, W_den, b_den, init_ch, ws, out);
}

// Round 5
// 551.747 us; speedup vs baseline: 1.3064x; 1.3064x over previous
//
#include <hip/hip_runtime.h>

#define BB 1024
#define FF 64
#define SS 512
#define HH 128
#define ZP 200          // z row pitch in bf16 elems (192 data + 8 pad; mult of 8 -> 16B-aligned b128)
#define ZROWS 16

typedef __attribute__((ext_vector_type(8))) short bf16x8;
typedef __attribute__((ext_vector_type(4))) float f32x4;

__device__ __forceinline__ unsigned short f2bf(float f) {
    unsigned int u = __float_as_uint(f);
    u += 0x7fff + ((u >> 16) & 1);          // RNE
    return (unsigned short)(u >> 16);
}

// ---------------------------------------------------------------------------
// Main recurrence. 256 blocks x 512 threads (8 waves, 1 block/CU, 2 waves/EU).
// Block owns 4 batch rows at M-rows {0,4,8,12}; each lane's acc[0] is its
// (row=b0+lq, col) element. Wave w owns hidden units [16w,16w+16).
// z = [x_hat(64) | h(128)]: x_hat = x (teacher rows) or pred feedback (auto).
// Weights are bf16 B-fragments in registers: wg[4][6]=96 VGPR + wd[4]=16.
// Two barriers/step; out-store deferred one step so its vmcnt drain hides
// under the next step's gate MFMAs.
// amdgpu_waves_per_eu(1): lift the 128-VGPR default cap (observed r1-r4:
// launch_bounds alone leaves the allocator at 128 and spills the weights).
// ---------------------------------------------------------------------------
__global__ __launch_bounds__(512) __attribute__((amdgpu_waves_per_eu(1)))
void lstm_mfma_kernel(const float* __restrict__ x,
                      const int* __restrict__ available_len,
                      const int* __restrict__ predict_len,
                      const float* __restrict__ W_ih,
                      const float* __restrict__ W_hh,
                      const float* __restrict__ b_ih,
                      const float* __restrict__ b_hh,
                      const float* __restrict__ W_den,
                      const float* __restrict__ b_den,
                      const float* __restrict__ init_ch,
                      float* __restrict__ out)
{
    const int b0  = blockIdx.x * 4;
    const int tid = threadIdx.x;
    const int w   = tid >> 6;          // wave 0..7
    const int l   = tid & 63;
    const int l16 = l & 15;
    const int lq  = l >> 4;            // 0..3
    const bool w4 = (w < 4);

    __shared__ __align__(16) unsigned short zbuf[2][ZROWS * ZP];

    for (int i = tid; i < 2 * ZROWS * ZP / 2; i += 512)
        ((unsigned int*)zbuf)[i] = 0u;

    const int p0 = predict_len[b0], p1 = predict_len[b0+1],
              p2 = predict_len[b0+2], p3 = predict_len[b0+3];
    const int maxP  = max(max(p0, p1), max(p2, p3));
    const int P_my  = predict_len[b0 + lq];     // lane's row (acc reg 0)
    const int AV_my = available_len[b0 + lq];

    // ---- gate weights: wg[gate][ktile 0..5], bf16, register-resident ----
    // gate col n = 128g + 16w + l16; k = 32kt + 8lq; k<64 -> W_ih, else W_hh
    bf16x8 wg[4][6];
    float bias[4];
    #pragma unroll
    for (int g = 0; g < 4; ++g) {
        const int n = 128*g + 16*w + l16;
        const float* rih = W_ih + n * FF;
        const float* rhh = W_hh + n * HH;
        #pragma unroll
        for (int kt = 0; kt < 6; ++kt) {
            const int k = 32*kt + 8*lq;
            const float* src = (k < 64) ? (rih + k) : (rhh + (k - 64));
            bf16x8 r;
            #pragma unroll
            for (int i = 0; i < 8; i++) r[i] = (short)f2bf(src[i]);
            wg[g][kt] = r;
        }
        bias[g] = b_ih[n] + b_hh[n];
    }

    // pred weights (waves 0-3): f = 16w + l16
    bf16x8 wd0, wd1, wd2, wd3;
    float bden = 0.f;
    size_t xbase = 0;
    int AV_x = 0;
    if (w4) {
        const int f = 16*w + l16;
        const float* rd = W_den + f * HH;
        bf16x8 r;
        #pragma unroll
        for (int i = 0; i < 8; i++) r[i] = (short)f2bf(rd[0*32 + 8*lq + i]);
        wd0 = r;
        #pragma unroll
        for (int i = 0; i < 8; i++) r[i] = (short)f2bf(rd[1*32 + 8*lq + i]);
        wd1 = r;
        #pragma unroll
        for (int i = 0; i < 8; i++) r[i] = (short)f2bf(rd[2*32 + 8*lq + i]);
        wd2 = r;
        #pragma unroll
        for (int i = 0; i < 8; i++) r[i] = (short)f2bf(rd[3*32 + 8*lq + i]);
        wd3 = r;
        bden = b_den[f];
        xbase = ((size_t)(b0 + w) * FF + l) * SS;   // x duty: row b0+w, feature l
        AV_x  = available_len[b0 + w];
    }

    const int unit = 16*w + l16;
    float c = init_ch[unit];
    const float h0v = init_ch[HH + unit];

    __syncthreads();                    // zeroing complete

    // init buf0: x_hat_0 = x[..,0] (AV >= 1 always), h_0
    zbuf[0][(4*lq)*ZP + 64 + unit] = f2bf(h0v);
    if (w4) zbuf[0][(4*w)*ZP + l] = f2bf(x[xbase]);

    float predreg = 0.f;
    int cur = 0;
    for (int t = 0; t < maxP; ++t) {
        __syncthreads();                               // B1: buf[cur]=(x_t,h_t)

        // deferred store of pred_{t-1}: drains under the gate MFMAs
        if (w4 && t > 0 && (t - 1) < P_my)
            out[(size_t)(t-1) * BB * FF + (size_t)(b0 + lq) * FF + 16*w + l16] = predreg;

        // x prefetch for t+1 (latency hidden under MFMAs)
        float xv = 0.f;
        const bool xl = w4 && (t + 1 < AV_x);
        if (xl) xv = x[xbase + t + 1];

        // A fragments from buf[cur]
        const unsigned short* zc = zbuf[cur];
        const int abase = l16*ZP + 8*lq;
        bf16x8 a0 = *(const bf16x8*)(zc + abase +   0);
        bf16x8 a1 = *(const bf16x8*)(zc + abase +  32);
        bf16x8 a2 = *(const bf16x8*)(zc + abase +  64);
        bf16x8 a3 = *(const bf16x8*)(zc + abase +  96);
        bf16x8 a4 = *(const bf16x8*)(zc + abase + 128);
        bf16x8 a5 = *(const bf16x8*)(zc + abase + 160);

        f32x4 ac0 = {0.f,0.f,0.f,0.f}, ac1 = {0.f,0.f,0.f,0.f},
              ac2 = {0.f,0.f,0.f,0.f}, ac3 = {0.f,0.f,0.f,0.f};
        ac0 = __builtin_amdgcn_mfma_f32_16x16x32_bf16(a0, wg[0][0], ac0, 0,0,0);
        ac1 = __builtin_amdgcn_mfma_f32_16x16x32_bf16(a0, wg[1][0], ac1, 0,0,0);
        ac2 = __builtin_amdgcn_mfma_f32_16x16x32_bf16(a0, wg[2][0], ac2, 0,0,0);
        ac3 = __builtin_amdgcn_mfma_f32_16x16x32_bf16(a0, wg[3][0], ac3, 0,0,0);
        ac0 = __builtin_amdgcn_mfma_f32_16x16x32_bf16(a1, wg[0][1], ac0, 0,0,0);
        ac1 = __builtin_amdgcn_mfma_f32_16x16x32_bf16(a1, wg[1][1], ac1, 0,0,0);
        ac2 = __builtin_amdgcn_mfma_f32_16x16x32_bf16(a1, wg[2][1], ac2, 0,0,0);
        ac3 = __builtin_amdgcn_mfma_f32_16x16x32_bf16(a1, wg[3][1], ac3, 0,0,0);
        ac0 = __builtin_amdgcn_mfma_f32_16x16x32_bf16(a2, wg[0][2], ac0, 0,0,0);
        ac1 = __builtin_amdgcn_mfma_f32_16x16x32_bf16(a2, wg[1][2], ac1, 0,0,0);
        ac2 = __builtin_amdgcn_mfma_f32_16x16x32_bf16(a2, wg[2][2], ac2, 0,0,0);
        ac3 = __builtin_amdgcn_mfma_f32_16x16x32_bf16(a2, wg[3][2], ac3, 0,0,0);
        ac0 = __builtin_amdgcn_mfma_f32_16x16x32_bf16(a3, wg[0][3], ac0, 0,0,0);
        ac1 = __builtin_amdgcn_mfma_f32_16x16x32_bf16(a3, wg[1][3], ac1, 0,0,0);
        ac2 = __builtin_amdgcn_mfma_f32_16x16x32_bf16(a3, wg[2][3], ac2, 0,0,0);
        ac3 = __builtin_amdgcn_mfma_f32_16x16x32_bf16(a3, wg[3][3], ac3, 0,0,0);
        ac0 = __builtin_amdgcn_mfma_f32_16x16x32_bf16(a4, wg[0][4], ac0, 0,0,0);
        ac1 = __builtin_amdgcn_mfma_f32_16x16x32_bf16(a4, wg[1][4], ac1, 0,0,0);
        ac2 = __builtin_amdgcn_mfma_f32_16x16x32_bf16(a4, wg[2][4], ac2, 0,0,0);
        ac3 = __builtin_amdgcn_mfma_f32_16x16x32_bf16(a4, wg[3][4], ac3, 0,0,0);
        ac0 = __builtin_amdgcn_mfma_f32_16x16x32_bf16(a5, wg[0][5], ac0, 0,0,0);
        ac1 = __builtin_amdgcn_mfma_f32_16x16x32_bf16(a5, wg[1][5], ac1, 0,0,0);
        ac2 = __builtin_amdgcn_mfma_f32_16x16x32_bf16(a5, wg[2][5], ac2, 0,0,0);
        ac3 = __builtin_amdgcn_mfma_f32_16x16x32_bf16(a5, wg[3][5], ac3, 0,0,0);

        // cell update (lane owns row b0+lq, unit 16w+l16; acc reg 0 only)
        const float g0 = ac0[0] + bias[0];
        const float g1 = ac1[0] + bias[1];
        const float g2 = ac2[0] + bias[2];
        const float g3 = ac3[0] + bias[3];
        const float si = 1.f / (1.f + __expf(-g0));
        const float sf = 1.f / (1.f + __expf(-g1));
        const float tg = 1.f - 2.f / (__expf(2.f * g2) + 1.f);
        const float so = 1.f / (1.f + __expf(-g3));
        const float cn = sf * c + si * tg;
        const float tc = 1.f - 2.f / (__expf(2.f * cn) + 1.f);
        const float hn = so * tc;

        const bool sel = (t < P_my);
        if (sel) c = cn;

        const int nxt = cur ^ 1;
        if (sel) zbuf[nxt][(4*lq)*ZP + 64 + unit] = f2bf(hn);   // h_{t+1}
        if (xl)  zbuf[nxt][(4*w)*ZP + l] = f2bf(xv);            // teacher x_{t+1}

        __syncthreads();                               // B2: buf[nxt] h ready

        if (w4) {
            // pred_t = W_den . h_{t+1} + b_den, from buf[nxt]
            const unsigned short* zn = zbuf[nxt];
            bf16x8 h0f = *(const bf16x8*)(zn + abase + 64 +  0);
            bf16x8 h1f = *(const bf16x8*)(zn + abase + 64 + 32);
            bf16x8 h2f = *(const bf16x8*)(zn + abase + 64 + 64);
            bf16x8 h3f = *(const bf16x8*)(zn + abase + 64 + 96);
            f32x4 pa = {0.f,0.f,0.f,0.f};
            pa = __builtin_amdgcn_mfma_f32_16x16x32_bf16(h0f, wd0, pa, 0,0,0);
            pa = __builtin_amdgcn_mfma_f32_16x16x32_bf16(h1f, wd1, pa, 0,0,0);
            pa = __builtin_amdgcn_mfma_f32_16x16x32_bf16(h2f, wd2, pa, 0,0,0);
            pa = __builtin_amdgcn_mfma_f32_16x16x32_bf16(h3f, wd3, pa, 0,0,0);
            predreg = pa[0] + bden;                    // stored next step
            // autoregressive feedback: x_hat_{t+1} = pred_t (auto rows)
            if (t + 1 >= AV_my && t < P_my)
                zbuf[nxt][(4*lq)*ZP + 16*w + l16] = f2bf(predreg);
        }
        cur = nxt;
    }
    // epilogue: store the last pred
    if (w4 && (maxP - 1) < P_my)
        out[(size_t)(maxP-1) * BB * FF + (size_t)(b0 + lq) * FF + 16*w + l16] = predreg;
}

// ---------------------------------------------------------------------------
// Tail: for t >= predict_len[b], out[t][b][f] = x[b][f][t].
// ---------------------------------------------------------------------------
__global__ void tail_copy(const float* __restrict__ x,
                          const int* __restrict__ predict_len,
                          float* __restrict__ out)
{
    __shared__ float tile[64][65];
    const int b  = blockIdx.x;
    const int t0 = blockIdx.y * 64;
    const int P  = predict_len[b];
    if (t0 + 64 <= P) return;

    const int tid = threadIdx.x;         // 256
    const int tt  = tid & 63;
    const int fb  = tid >> 6;
    #pragma unroll
    for (int i = 0; i < 16; i++) {
        int f = fb * 16 + i;
        tile[f][tt] = x[(size_t)b * FF * SS + (size_t)f * SS + t0 + tt];
    }
    __syncthreads();
    const int f2 = tid & 63;
    const int tb = tid >> 6;
    #pragma unroll
    for (int i = 0; i < 16; i++) {
        int tloc = tb * 16 + i;
        int t    = t0 + tloc;
        if (t >= P) out[(size_t)t * BB * FF + (size_t)b * FF + f2] = tile[f2][tloc];
    }
}

extern "C" void kernel_launch(void* const* d_in, const int* in_sizes, int n_in,
                              void* d_out, int out_size, void* d_ws, size_t ws_size,
                              hipStream_t stream) {
    const float* x       = (const float*)d_in[0];
    const int*   avail   = (const int*)  d_in[1];
    const int*   plen    = (const int*)  d_in[2];
    const float* W_ih    = (const float*)d_in[3];
    const float* W_hh    = (const float*)d_in[4];
    const float* b_ih    = (const float*)d_in[5];
    const float* b_hh    = (const float*)d_in[6];
    const float* W_den   = (const float*)d_in[7];
    const float* b_den   = (const float*)d_in[8];
    const float* init_ch = (const float*)d_in[9];
    float*       out     = (float*)d_out;

    tail_copy<<<dim3(BB, SS/64), dim3(256), 0, stream>>>(x, plen, out);
    lstm_mfma_kernel<<<dim3(BB/4), dim3(512), 0, stream>>>(
        x, avail, plen, W_ih, W_hh, b_ih, b_hh, W_den, b_den, init_ch, out);
}

// Round 6
// 487.496 us; speedup vs baseline: 1.4786x; 1.1318x over previous
//
#include <hip/hip_runtime.h>

#define BB 1024
#define FF 64
#define SS 512
#define HH 128
#define ZP 200          // z row pitch in bf16 elems (192 data + 8 pad; 16B-aligned rows)
#define ZROWS 16
#define OUTSTRIDE (BB*FF)

typedef __attribute__((ext_vector_type(8))) short bf16x8;
typedef __attribute__((ext_vector_type(4))) float f32x4;

__device__ __forceinline__ unsigned short f2bf(float f) {
    unsigned int u = __float_as_uint(f);
    u += 0x7fff + ((u >> 16) & 1);          // RNE
    return (unsigned short)(u >> 16);
}

// Raw barrier with LDS-only drain: producers' ds_writes complete (lgkmcnt(0))
// before arrival; global loads/stores stay in flight across the barrier
// (unlike __syncthreads, which drains vmcnt(0) and serialized every step).
// sched_barrier(0) fences the compiler from hoisting post-barrier ds_reads
// or sinking pre-barrier ds_writes (rule #18).
__device__ __forceinline__ void bar_lds() {
    asm volatile("s_waitcnt lgkmcnt(0)" ::: "memory");
    __builtin_amdgcn_s_barrier();
    __builtin_amdgcn_sched_barrier(0);
}

// ---------------------------------------------------------------------------
// 256 blocks x 512 threads (8 waves, 1 block/CU). Block owns 4 batch rows at
// M-rows {0,4,8,12}; lane's acc[0] = (row b0+lq, col). Wave w owns hidden
// units [16w,16w+16). z = [x_hat(64) | h(128)] bf16 in LDS, double-buffered.
// Weight B-fragments register-resident (wg 96 + wd 16 regs -> AGPR file).
// Two raw barriers per step; x loaded as float4 once per 4 steps (unrolled
// body, static indices); out-store issued right after pred, drains freely.
// ---------------------------------------------------------------------------
__global__ __launch_bounds__(512)
void lstm_mfma_kernel(const float* __restrict__ x,
                      const int* __restrict__ available_len,
                      const int* __restrict__ predict_len,
                      const float* __restrict__ W_ih,
                      const float* __restrict__ W_hh,
                      const float* __restrict__ b_ih,
                      const float* __restrict__ b_hh,
                      const float* __restrict__ W_den,
                      const float* __restrict__ b_den,
                      const float* __restrict__ init_ch,
                      float* __restrict__ out)
{
    const int b0  = blockIdx.x * 4;
    const int tid = threadIdx.x;
    const int w   = tid >> 6;          // wave 0..7
    const int l   = tid & 63;
    const int l16 = l & 15;
    const int lq  = l >> 4;            // 0..3
    const bool w4 = (w < 4);

    __shared__ __align__(16) unsigned short zbuf[2][ZROWS * ZP];

    for (int i = tid; i < 2 * ZROWS * ZP / 2; i += 512)
        ((unsigned int*)zbuf)[i] = 0u;

    const int p0 = predict_len[b0], p1 = predict_len[b0+1],
              p2 = predict_len[b0+2], p3 = predict_len[b0+3];
    const int maxP  = max(max(p0, p1), max(p2, p3));
    const int P_my  = predict_len[b0 + lq];     // lane's row (acc reg 0)
    const int AV_my = available_len[b0 + lq];

    // ---- gate weights: wg[gate][ktile 0..5], bf16, register-resident ----
    bf16x8 wg[4][6];
    float bias[4];
    #pragma unroll
    for (int g = 0; g < 4; ++g) {
        const int n = 128*g + 16*w + l16;
        const float* rih = W_ih + n * FF;
        const float* rhh = W_hh + n * HH;
        #pragma unroll
        for (int kt = 0; kt < 6; ++kt) {
            const int k = 32*kt + 8*lq;
            const float* src = (k < 64) ? (rih + k) : (rhh + (k - 64));
            bf16x8 r;
            #pragma unroll
            for (int i = 0; i < 8; i++) r[i] = (short)f2bf(src[i]);
            wg[g][kt] = r;
        }
        bias[g] = b_ih[n] + b_hh[n];
    }

    // pred weights (waves 0-3): f = 16w + l16
    bf16x8 wd0, wd1, wd2, wd3;
    float bden = 0.f;
    size_t xbase = 0;
    int AV_x = 0;
    if (w4) {
        const int f = 16*w + l16;
        const float* rd = W_den + f * HH;
        bf16x8 r;
        #pragma unroll
        for (int i = 0; i < 8; i++) r[i] = (short)f2bf(rd[0*32 + 8*lq + i]);
        wd0 = r;
        #pragma unroll
        for (int i = 0; i < 8; i++) r[i] = (short)f2bf(rd[1*32 + 8*lq + i]);
        wd1 = r;
        #pragma unroll
        for (int i = 0; i < 8; i++) r[i] = (short)f2bf(rd[2*32 + 8*lq + i]);
        wd2 = r;
        #pragma unroll
        for (int i = 0; i < 8; i++) r[i] = (short)f2bf(rd[3*32 + 8*lq + i]);
        wd3 = r;
        bden = b_den[f];
        xbase = ((size_t)(b0 + w) * FF + l) * SS;   // x duty: row b0+w, feature l
        AV_x  = available_len[b0 + w];
    }

    const int unit  = 16*w + l16;
    const int abase = l16*ZP + 8*lq;
    float c = init_ch[unit];
    const float h0v = init_ch[HH + unit];
    float* outb = out + (size_t)(b0 + lq) * FF + 16*w + l16;

    bar_lds();                          // zeroing visible before init writes

    zbuf[0][(4*lq)*ZP + 64 + unit] = f2bf(h0v);
    if (w4) zbuf[0][(4*w)*ZP + l] = f2bf(x[xbase]);

    float4 qc = {0.f,0.f,0.f,0.f};
    if (w4 && AV_x > 1) qc = *(const float4*)(x + xbase);   // x_0..x_3

    int cur = 0;

#define DO_STEP(S, XNEXT)                                                      \
  do {                                                                         \
    const int s_ = (S);                                                        \
    bar_lds();                                          /* B1: buf[cur] */     \
    const unsigned short* zc_ = zbuf[cur];                                     \
    bf16x8 a0 = *(const bf16x8*)(zc_ + abase +   0);                           \
    bf16x8 a1 = *(const bf16x8*)(zc_ + abase +  32);                           \
    bf16x8 a2 = *(const bf16x8*)(zc_ + abase +  64);                           \
    bf16x8 a3 = *(const bf16x8*)(zc_ + abase +  96);                           \
    bf16x8 a4 = *(const bf16x8*)(zc_ + abase + 128);                           \
    bf16x8 a5 = *(const bf16x8*)(zc_ + abase + 160);                           \
    f32x4 ac0 = {0.f,0.f,0.f,0.f}, ac1 = {0.f,0.f,0.f,0.f},                    \
          ac2 = {0.f,0.f,0.f,0.f}, ac3 = {0.f,0.f,0.f,0.f};                    \
    ac0 = __builtin_amdgcn_mfma_f32_16x16x32_bf16(a0, wg[0][0], ac0, 0,0,0);   \
    ac1 = __builtin_amdgcn_mfma_f32_16x16x32_bf16(a0, wg[1][0], ac1, 0,0,0);   \
    ac2 = __builtin_amdgcn_mfma_f32_16x16x32_bf16(a0, wg[2][0], ac2, 0,0,0);   \
    ac3 = __builtin_amdgcn_mfma_f32_16x16x32_bf16(a0, wg[3][0], ac3, 0,0,0);   \
    ac0 = __builtin_amdgcn_mfma_f32_16x16x32_bf16(a1, wg[0][1], ac0, 0,0,0);   \
    ac1 = __builtin_amdgcn_mfma_f32_16x16x32_bf16(a1, wg[1][1], ac1, 0,0,0);   \
    ac2 = __builtin_amdgcn_mfma_f32_16x16x32_bf16(a1, wg[2][1], ac2, 0,0,0);   \
    ac3 = __builtin_amdgcn_mfma_f32_16x16x32_bf16(a1, wg[3][1], ac3, 0,0,0);   \
    ac0 = __builtin_amdgcn_mfma_f32_16x16x32_bf16(a2, wg[0][2], ac0, 0,0,0);   \
    ac1 = __builtin_amdgcn_mfma_f32_16x16x32_bf16(a2, wg[1][2], ac1, 0,0,0);   \
    ac2 = __builtin_amdgcn_mfma_f32_16x16x32_bf16(a2, wg[2][2], ac2, 0,0,0);   \
    ac3 = __builtin_amdgcn_mfma_f32_16x16x32_bf16(a2, wg[3][2], ac3, 0,0,0);   \
    ac0 = __builtin_amdgcn_mfma_f32_16x16x32_bf16(a3, wg[0][3], ac0, 0,0,0);   \
    ac1 = __builtin_amdgcn_mfma_f32_16x16x32_bf16(a3, wg[1][3], ac1, 0,0,0);   \
    ac2 = __builtin_amdgcn_mfma_f32_16x16x32_bf16(a3, wg[2][3], ac2, 0,0,0);   \
    ac3 = __builtin_amdgcn_mfma_f32_16x16x32_bf16(a3, wg[3][3], ac3, 0,0,0);   \
    ac0 = __builtin_amdgcn_mfma_f32_16x16x32_bf16(a4, wg[0][4], ac0, 0,0,0);   \
    ac1 = __builtin_amdgcn_mfma_f32_16x16x32_bf16(a4, wg[1][4], ac1, 0,0,0);   \
    ac2 = __builtin_amdgcn_mfma_f32_16x16x32_bf16(a4, wg[2][4], ac2, 0,0,0);   \
    ac3 = __builtin_amdgcn_mfma_f32_16x16x32_bf16(a4, wg[3][4], ac3, 0,0,0);   \
    ac0 = __builtin_amdgcn_mfma_f32_16x16x32_bf16(a5, wg[0][5], ac0, 0,0,0);   \
    ac1 = __builtin_amdgcn_mfma_f32_16x16x32_bf16(a5, wg[1][5], ac1, 0,0,0);   \
    ac2 = __builtin_amdgcn_mfma_f32_16x16x32_bf16(a5, wg[2][5], ac2, 0,0,0);   \
    ac3 = __builtin_amdgcn_mfma_f32_16x16x32_bf16(a5, wg[3][5], ac3, 0,0,0);   \
    const float g0 = ac0[0] + bias[0];                                         \
    const float g1 = ac1[0] + bias[1];                                         \
    const float g2 = ac2[0] + bias[2];                                         \
    const float g3 = ac3[0] + bias[3];                                         \
    const float si = 1.f / (1.f + __expf(-g0));                                \
    const float sf = 1.f / (1.f + __expf(-g1));                                \
    const float tg = 1.f - 2.f / (__expf(2.f * g2) + 1.f);                     \
    const float so = 1.f / (1.f + __expf(-g3));                                \
    const float cn = sf * c + si * tg;                                         \
    const float tc = 1.f - 2.f / (__expf(2.f * cn) + 1.f);                     \
    const float hn = so * tc;                                                  \
    const int nxt_ = cur ^ 1;                                                  \
    if (s_ < P_my) { c = cn; zbuf[nxt_][(4*lq)*ZP + 64 + unit] = f2bf(hn); }   \
    bar_lds();                                          /* B2: h ready */      \
    if (w4) {                                                                  \
      const unsigned short* zn_ = zbuf[nxt_];                                  \
      bf16x8 h0f = *(const bf16x8*)(zn_ + abase + 64 +  0);                    \
      bf16x8 h1f = *(const bf16x8*)(zn_ + abase + 64 + 32);                    \
      bf16x8 h2f = *(const bf16x8*)(zn_ + abase + 64 + 64);                    \
      bf16x8 h3f = *(const bf16x8*)(zn_ + abase + 64 + 96);                    \
      f32x4 pa = {0.f,0.f,0.f,0.f}, pb = {0.f,0.f,0.f,0.f};                    \
      pa = __builtin_amdgcn_mfma_f32_16x16x32_bf16(h0f, wd0, pa, 0,0,0);       \
      pb = __builtin_amdgcn_mfma_f32_16x16x32_bf16(h2f, wd2, pb, 0,0,0);       \
      pa = __builtin_amdgcn_mfma_f32_16x16x32_bf16(h1f, wd1, pa, 0,0,0);       \
      pb = __builtin_amdgcn_mfma_f32_16x16x32_bf16(h3f, wd3, pb, 0,0,0);       \
      const float pred_ = pa[0] + pb[0] + bden;                                \
      if (s_ < P_my) {                                                         \
        outb[(size_t)s_ * OUTSTRIDE] = pred_;                                  \
        if (s_ + 1 >= AV_my)                                                   \
          zbuf[nxt_][(4*lq)*ZP + 16*w + l16] = f2bf(pred_);                    \
      }                                                                        \
      if (s_ + 1 < AV_x) zbuf[nxt_][(4*w)*ZP + l] = f2bf(XNEXT);               \
    }                                                                          \
    cur = nxt_;                                                                \
  } while (0)

    int t4 = 0;
    for (; t4 + 4 <= maxP; t4 += 4) {
        float4 qn = {0.f,0.f,0.f,0.f};
        if (w4 && (t4 + 4 < AV_x))
            qn = *(const float4*)(x + xbase + t4 + 4);   // x_{t4+4}..x_{t4+7}
        DO_STEP(t4 + 0, qc.y);
        DO_STEP(t4 + 1, qc.z);
        DO_STEP(t4 + 2, qc.w);
        DO_STEP(t4 + 3, qn.x);
        qc = qn;
    }
    for (; t4 < maxP; ++t4) {
        float xs = 0.f;
        if (w4 && (t4 + 1 < AV_x)) xs = x[xbase + t4 + 1];
        DO_STEP(t4, xs);
    }
#undef DO_STEP
}

// ---------------------------------------------------------------------------
// Tail: for t >= predict_len[b], out[t][b][f] = x[b][f][t].
// ---------------------------------------------------------------------------
__global__ void tail_copy(const float* __restrict__ x,
                          const int* __restrict__ predict_len,
                          float* __restrict__ out)
{
    __shared__ float tile[64][65];
    const int b  = blockIdx.x;
    const int t0 = blockIdx.y * 64;
    const int P  = predict_len[b];
    if (t0 + 64 <= P) return;

    const int tid = threadIdx.x;         // 256
    const int tt  = tid & 63;
    const int fb  = tid >> 6;
    #pragma unroll
    for (int i = 0; i < 16; i++) {
        int f = fb * 16 + i;
        tile[f][tt] = x[(size_t)b * FF * SS + (size_t)f * SS + t0 + tt];
    }
    __syncthreads();
    const int f2 = tid & 63;
    const int tb = tid >> 6;
    #pragma unroll
    for (int i = 0; i < 16; i++) {
        int tloc = tb * 16 + i;
        int t    = t0 + tloc;
        if (t >= P) out[(size_t)t * BB * FF + (size_t)b * FF + f2] = tile[f2][tloc];
    }
}

extern "C" void kernel_launch(void* const* d_in, const int* in_sizes, int n_in,
                              void* d_out, int out_size, void* d_ws, size_t ws_size,
                              hipStream_t stream) {
    const float* x       = (const float*)d_in[0];
    const int*   avail   = (const int*)  d_in[1];
    const int*   plen    = (const int*)  d_in[2];
    const float* W_ih    = (const float*)d_in[3];
    const float* W_hh    = (const float*)d_in[4];
    const float* b_ih    = (const float*)d_in[5];
    const float* b_hh    = (const float*)d_in[6];
    const float* W_den   = (const float*)d_in[7];
    const float* b_den   = (const float*)d_in[8];
    const float* init_ch = (const float*)d_in[9];
    float*       out     = (float*)d_out;

    tail_copy<<<dim3(BB, SS/64), dim3(256), 0, stream>>>(x, plen, out);
    lstm_mfma_kernel<<<dim3(BB/4), dim3(512), 0, stream>>>(
        x, avail, plen, W_ih, W_hh, b_ih, b_hh, W_den, b_den, init_ch, out);
}